// Round 1
// baseline (9041.697 us; speedup 1.0000x reference)
//
#include <hip/hip_runtime.h>
#include <cstdint>
#include <cstddef>

#define B 64
#define H 1024
#define V 32000
#define T 50

__device__ __forceinline__ float sigmoidf_(float x) { return 1.0f / (1.0f + expf(-x)); }

// ---------------------------------------------------------------------------
// init: ws is re-poisoned before every call; rebuild all state.
// h_t/c_t stored transposed [H][B] so b is the fast (coalesced) dim.
// ---------------------------------------------------------------------------
__global__ void k_init(const float* __restrict__ h_in, const float* __restrict__ c_in,
                       float* __restrict__ h_t, float* __restrict__ c_t,
                       int* __restrict__ tok, int* __restrict__ active,
                       unsigned long long* __restrict__ keys, float* __restrict__ out)
{
    int idx = blockIdx.x * 256 + threadIdx.x;
    if (idx < B * H) {
        int b = idx >> 10, k = idx & 1023;
        h_t[k * B + b] = h_in[idx];
        c_t[k * B + b] = c_in[idx];
    }
    if (idx < T * B) out[idx] = 0.0f;       // tok_out defaults to 0 (inactive steps)
    if (idx < B) { tok[idx] = 1; keys[idx] = 0ull; }  // SOS token
    if (idx == 0) *active = 1;
}

// ---------------------------------------------------------------------------
// gates GEMM: part[s][j][b] partials, j = g*1024+k, 4-way K-split (s).
// s<2: A = emb[tok[b]] (x), rows h in [s*512, s*512+512), weights w_ih
// s>=2: A = h_prev,            rows h in [(s-2)*512, ...),  weights w_hh
// block: 256 thr, tile 64 cols x 64 b x K=512. grid (64, 4).
// ---------------------------------------------------------------------------
__global__ __launch_bounds__(256) void k_gates(
    const float* __restrict__ emb, const float* __restrict__ w_ih,
    const float* __restrict__ w_hh, const float* __restrict__ h_t,
    const int* __restrict__ tok, const int* __restrict__ active,
    float* __restrict__ part)
{
    if (!*active) return;
    const int tid  = threadIdx.x;
    const int s    = blockIdx.y;
    const int j0   = blockIdx.x * 64;
    const int g    = j0 >> 10;
    const int col0 = j0 & 1023;
    const float* Wm = ((s < 2) ? w_ih : w_hh) + (size_t)g * H * H;
    const int hbase = (s & 1) * 512;

    __shared__ float a_s[32][68];   // [hh][b], padded stride for b128 reads
    __shared__ float w_s[32][64];   // [hh][c]

    const int cq = tid & 15;        // 4 cols per thread
    const int bq = tid >> 4;        // 4 b per thread
    float acc[4][4];
    #pragma unroll
    for (int i = 0; i < 4; ++i)
        #pragma unroll
        for (int j = 0; j < 4; ++j) acc[i][j] = 0.0f;

    const float* erow_base = (s < 2) ? (emb + (size_t)tok[tid >> 2] * H) : nullptr;

    for (int ch = 0; ch < 16; ++ch) {
        const int h0 = hbase + ch * 32;
        {   // stage weights: coalesced (c fast)
            const int c = tid & 63, hh0 = tid >> 6;
            #pragma unroll
            for (int i = 0; i < 8; ++i)
                w_s[hh0 + 4 * i][c] = Wm[(size_t)(h0 + hh0 + 4 * i) * H + col0 + c];
        }
        if (s < 2) {  // x = emb gather: read along h per b (coalesced per row)
            const int sub = tid & 3;
            const float* er = erow_base + h0 + sub * 8;
            const int b = tid >> 2;
            float4 v0 = *reinterpret_cast<const float4*>(er);
            float4 v1 = *reinterpret_cast<const float4*>(er + 4);
            a_s[sub * 8 + 0][b] = v0.x; a_s[sub * 8 + 1][b] = v0.y;
            a_s[sub * 8 + 2][b] = v0.z; a_s[sub * 8 + 3][b] = v0.w;
            a_s[sub * 8 + 4][b] = v1.x; a_s[sub * 8 + 5][b] = v1.y;
            a_s[sub * 8 + 6][b] = v1.z; a_s[sub * 8 + 7][b] = v1.w;
        } else {      // h_prev already transposed [H][B]: coalesced over b
            const int b = tid & 63, hh0 = tid >> 6;
            #pragma unroll
            for (int i = 0; i < 8; ++i)
                a_s[hh0 + 4 * i][b] = h_t[(size_t)(h0 + hh0 + 4 * i) * B + b];
        }
        __syncthreads();
        #pragma unroll
        for (int hh = 0; hh < 32; ++hh) {
            float4 av = *reinterpret_cast<const float4*>(&a_s[hh][bq * 4]);
            float4 wv = *reinterpret_cast<const float4*>(&w_s[hh][cq * 4]);
            float a4[4] = {av.x, av.y, av.z, av.w};
            float w4[4] = {wv.x, wv.y, wv.z, wv.w};
            #pragma unroll
            for (int ci = 0; ci < 4; ++ci)
                #pragma unroll
                for (int bi = 0; bi < 4; ++bi)
                    acc[ci][bi] += w4[ci] * a4[bi];
        }
        __syncthreads();
    }
    #pragma unroll
    for (int ci = 0; ci < 4; ++ci) {
        float4 st = make_float4(acc[ci][0], acc[ci][1], acc[ci][2], acc[ci][3]);
        *reinterpret_cast<float4*>(
            &part[(size_t)((s << 12) + j0 + cq * 4 + ci) * B + bq * 4]) = st;
    }
}

// ---------------------------------------------------------------------------
// combine partials + biases + activations; update h,c (transposed layout).
// ---------------------------------------------------------------------------
__global__ __launch_bounds__(256) void k_combine(
    const float* __restrict__ part, const float* __restrict__ b_ih,
    const float* __restrict__ b_hh, float* __restrict__ h_t,
    float* __restrict__ c_t, const int* __restrict__ active)
{
    if (!*active) return;
    const int idx = blockIdx.x * 256 + threadIdx.x;   // 0..65535
    const int b = idx & 63, k = idx >> 6;
    float gv[4];
    #pragma unroll
    for (int g = 0; g < 4; ++g) {
        float v = b_ih[g * H + k] + b_hh[g * H + k];
        #pragma unroll
        for (int s = 0; s < 4; ++s)
            v += part[(size_t)((s << 12) + (g << 10) + k) * B + b];
        gv[g] = v;
    }
    const float ig = sigmoidf_(gv[0]);
    const float fg = sigmoidf_(gv[1]);
    const float cg = tanhf(gv[2]);
    const float og = sigmoidf_(gv[3]);
    const float c  = c_t[k * B + b];
    const float cn = fg * c + ig * cg;
    const float hn = og * tanhf(cn);
    c_t[k * B + b] = cn;
    h_t[k * B + b] = hn;
}

// ---------------------------------------------------------------------------
// logits GEMM + fused argmax. tile 64 v x 64 b x K=1024, grid 500.
// argmax key: monotonic-float<<32 | (0x7FFFFFFF - v)  -> atomicMax gives
// max value, ties -> smallest v (matches jnp.argmax first-occurrence).
// ---------------------------------------------------------------------------
__global__ __launch_bounds__(256) void k_logits(
    const float* __restrict__ h_t, const float* __restrict__ out_w,
    const float* __restrict__ out_b, const float* __restrict__ std_,
    unsigned long long* __restrict__ keys, const int* __restrict__ active,
    int t)
{
    if (!*active) return;
    const int tid = threadIdx.x;
    const int v0  = blockIdx.x * 64;
    __shared__ float a_s[32][68];
    __shared__ float w_s[32][64];
    const int cq = tid & 15;   // 4 v-cols
    const int bq = tid >> 4;   // 4 b-rows
    float acc[4][4];
    #pragma unroll
    for (int i = 0; i < 4; ++i)
        #pragma unroll
        for (int j = 0; j < 4; ++j) acc[i][j] = 0.0f;

    for (int ch = 0; ch < 32; ++ch) {
        const int h0 = ch * 32;
        const int c = tid & 63, hh0 = tid >> 6;
        #pragma unroll
        for (int i = 0; i < 8; ++i)
            w_s[hh0 + 4 * i][c] = out_w[(size_t)(h0 + hh0 + 4 * i) * V + v0 + c];
        #pragma unroll
        for (int i = 0; i < 8; ++i)
            a_s[hh0 + 4 * i][c] = h_t[(size_t)(h0 + hh0 + 4 * i) * B + c];
        __syncthreads();
        #pragma unroll
        for (int hh = 0; hh < 32; ++hh) {
            float4 av = *reinterpret_cast<const float4*>(&a_s[hh][bq * 4]);
            float4 wv = *reinterpret_cast<const float4*>(&w_s[hh][cq * 4]);
            float a4[4] = {av.x, av.y, av.z, av.w};
            float w4[4] = {wv.x, wv.y, wv.z, wv.w};
            #pragma unroll
            for (int ci = 0; ci < 4; ++ci)
                #pragma unroll
                for (int bi = 0; bi < 4; ++bi)
                    acc[ci][bi] += w4[ci] * a4[bi];
        }
        __syncthreads();
    }

    const float4 ob = *reinterpret_cast<const float4*>(&out_b[v0 + cq * 4]);
    const float obv[4] = {ob.x, ob.y, ob.z, ob.w};
    unsigned long long bestkey[4];
    #pragma unroll
    for (int bi = 0; bi < 4; ++bi) {
        const int b = bq * 4 + bi;
        const float4 sv = *reinterpret_cast<const float4*>(
            &std_[((size_t)t * B + b) * V + v0 + cq * 4]);
        const float s4[4] = {sv.x, sv.y, sv.z, sv.w};
        float bv = 0.0f; int bc = 0;
        #pragma unroll
        for (int ci = 0; ci < 4; ++ci) {
            const float val = acc[ci][bi] + obv[ci] + s4[ci];
            if (ci == 0 || val > bv) { bv = val; bc = ci; }  // strict >: first max
        }
        const uint32_t fb = __float_as_uint(bv);
        const uint32_t mk = (fb & 0x80000000u) ? ~fb : (fb | 0x80000000u);
        unsigned long long key = ((unsigned long long)mk << 32)
                               | (unsigned)(0x7FFFFFFF - (v0 + cq * 4 + bc));
        #pragma unroll
        for (int off = 8; off > 0; off >>= 1) {
            unsigned long long o = __shfl_xor(key, off, 16);
            if (o > key) key = o;
        }
        bestkey[bi] = key;
    }
    if (cq == 0) {
        #pragma unroll
        for (int bi = 0; bi < 4; ++bi)
            atomicMax(&keys[bq * 4 + bi], bestkey[bi]);
    }
}

// ---------------------------------------------------------------------------
// per-step finalize: decode argmax, emit token, update active flag.
// ---------------------------------------------------------------------------
__global__ void k_step_final(unsigned long long* __restrict__ keys,
                             int* __restrict__ tok, int* __restrict__ active,
                             float* __restrict__ out, int t)
{
    const int b = threadIdx.x;  // 64 threads = one wave
    if (*active) {
        const unsigned long long kk = keys[b];
        const int tn = 0x7FFFFFFF - (int)(unsigned)(kk & 0xFFFFFFFFull);
        out[t * B + b] = (float)tn;
        tok[b] = tn;
        const unsigned long long anyMask = __ballot(tn > 0);
        keys[b] = 0ull;                      // reset for next step
        if (b == 0 && anyMask == 0ull) *active = 0;
    }
}

// final h: transpose back to [B][H] at out[T*B ...]
__global__ void k_fin(const float* __restrict__ h_t, float* __restrict__ out)
{
    const int idx = blockIdx.x * 256 + threadIdx.x;  // 65536
    const int b = idx >> 10, k = idx & 1023;
    out[T * B + idx] = h_t[k * B + b];
}

extern "C" void kernel_launch(void* const* d_in, const int* in_sizes, int n_in,
                              void* d_out, int out_size, void* d_ws, size_t ws_size,
                              hipStream_t stream)
{
    // inputs: 0 encoder_output (unused), 1 std, 2 h, 3 c, 4 emb,
    //         5 w_ih, 6 w_hh, 7 b_ih, 8 b_hh, 9 out_w, 10 out_b
    const float* std_  = (const float*)d_in[1];
    const float* h_in  = (const float*)d_in[2];
    const float* c_in  = (const float*)d_in[3];
    const float* emb   = (const float*)d_in[4];
    const float* w_ih  = (const float*)d_in[5];
    const float* w_hh  = (const float*)d_in[6];
    const float* b_ih  = (const float*)d_in[7];
    const float* b_hh  = (const float*)d_in[8];
    const float* out_w = (const float*)d_in[9];
    const float* out_b = (const float*)d_in[10];
    float* out = (float*)d_out;

    // ws layout (≈4.72 MB): h_t | c_t | part[4][4096][64] | keys | tok | active
    float* h_t  = (float*)d_ws;
    float* c_t  = h_t + B * H;
    float* part = c_t + B * H;
    unsigned long long* keys = (unsigned long long*)(part + 4 * 4096 * B);
    int* tok    = (int*)(keys + B);
    int* active = tok + B;

    k_init<<<256, 256, 0, stream>>>(h_in, c_in, h_t, c_t, tok, active, keys, out);
    for (int t = 0; t < T; ++t) {
        k_gates<<<dim3(64, 4), 256, 0, stream>>>(emb, w_ih, w_hh, h_t, tok, active, part);
        k_combine<<<256, 256, 0, stream>>>(part, b_ih, b_hh, h_t, c_t, active);
        k_logits<<<V / 64, 256, 0, stream>>>(h_t, out_w, out_b, std_, keys, active, t);
        k_step_final<<<1, 64, 0, stream>>>(keys, tok, active, out, t);
    }
    k_fin<<<256, 256, 0, stream>>>(h_t, out);
}

// Round 2
// 4148.671 us; speedup vs baseline: 2.1794x; 2.1794x over previous
//
#include <hip/hip_runtime.h>
#include <cstdint>
#include <cstddef>

#define B 64
#define H 1024
#define V 32000
#define T 50
#define VT 2000          // V/16 tiles
#define GNT 256          // 4096/16 gate col tiles
#define SW 16.0f         // weight pre-scale (avoid fp16 subnormals)
#define SL 2048.0f       // lo-word scale
#define INV_HI (1.0f/16.0f)
#define INV_LO (1.0f/32768.0f)

typedef _Float16 f16;
typedef _Float16 half8 __attribute__((ext_vector_type(8)));
typedef float f32x4 __attribute__((ext_vector_type(4)));

__device__ __forceinline__ float sigmoidf_(float x) { return 1.0f / (1.0f + expf(-x)); }

// Fragment index helpers (16x16x32 f16 MFMA):
// A: lane holds A[m=lane&15][k=quad*8+j]   -> A_pack[((chunk*4+mt)*64+lane)*8+j]
// B: lane holds B[k=quad*8+j][n=lane&15]   -> W_pack[((ntile*NCH+chunk)*64+lane)*8+j]
// C/D: col(n)=lane&15, row(m)=quad*4+reg   [measured m89/m91]

// ---------------------------------------------------------------------------
// pack out_w [H][V] fp32 -> hi/lo fp16 B-fragments (scaled by SW, lo by SL)
// ---------------------------------------------------------------------------
__global__ __launch_bounds__(256) void k_packw(const float* __restrict__ out_w,
                                               f16* __restrict__ Whi, f16* __restrict__ Wlo)
{
    const int vt = blockIdx.x >> 3, cg = blockIdx.x & 7;
    const int chunk = cg * 4 + (threadIdx.x >> 6);
    const int q = (threadIdx.x >> 4) & 3, vl = threadIdx.x & 15;
    const int lane = q * 16 + vl;
    half8 h8, l8;
    #pragma unroll
    for (int j = 0; j < 8; ++j) {
        const int k = chunk * 32 + q * 8 + j;
        const float w = out_w[(size_t)k * V + vt * 16 + vl] * SW;
        const f16 hi = (f16)w;
        h8[j] = hi;
        l8[j] = (f16)((w - (float)hi) * SL);
    }
    const size_t pos = ((size_t)(vt * 32 + chunk) * 64 + lane) * 8;
    *(half8*)&Whi[pos] = h8;
    *(half8*)&Wlo[pos] = l8;
}

// ---------------------------------------------------------------------------
// pack gate weights: W_cat[K=2048][N'=4096], K<1024 -> w_ih, else w_hh.
// column permutation: n' = blk*16 + kk*4 + g  <->  (g, k = blk*4+kk)
// ---------------------------------------------------------------------------
__global__ __launch_bounds__(256) void k_packg(const float* __restrict__ w_ih,
                                               const float* __restrict__ w_hh,
                                               f16* __restrict__ Ghi, f16* __restrict__ Glo)
{
    const int nt = blockIdx.x >> 4, cg = blockIdx.x & 15;
    const int chunk = cg * 4 + (threadIdx.x >> 6);
    const int q = (threadIdx.x >> 4) & 3, vl = threadIdx.x & 15;
    const int lane = q * 16 + vl;
    const int kk = vl >> 2, g = vl & 3;
    const int kcol = nt * 4 + kk;
    half8 h8, l8;
    #pragma unroll
    for (int j = 0; j < 8; ++j) {
        const int K = chunk * 32 + q * 8 + j;
        const float w = ((K < 1024)
            ? w_ih[(size_t)g * H * H + (size_t)K * H + kcol]
            : w_hh[(size_t)g * H * H + (size_t)(K - 1024) * H + kcol]) * SW;
        const f16 hi = (f16)w;
        h8[j] = hi;
        l8[j] = (f16)((w - (float)hi) * SL);
    }
    const size_t pos = ((size_t)(nt * 64 + chunk) * 64 + lane) * 8;
    *(half8*)&Ghi[pos] = h8;
    *(half8*)&Glo[pos] = l8;
}

__global__ void k_packbias(const float* __restrict__ b_ih, const float* __restrict__ b_hh,
                           float* __restrict__ biasp)
{
    const int n = blockIdx.x * 256 + threadIdx.x;   // 4096
    const int blk = n >> 4, rem = n & 15, kk = rem >> 2, g = rem & 3;
    const int kcol = blk * 4 + kk;
    biasp[n] = b_ih[g * H + kcol] + b_hh[g * H + kcol];
}

// ---------------------------------------------------------------------------
// init: transpose h,c; pack h -> Ah[0]; pack emb[SOS=1] -> Ax; flags.
// blocks 0..63 = per-b, block 64 = misc.
// ---------------------------------------------------------------------------
__global__ void k_init(const float* __restrict__ h_in, const float* __restrict__ c_in,
                       const float* __restrict__ emb,
                       float* __restrict__ h_t, float* __restrict__ c_t,
                       f16* __restrict__ Axh, f16* __restrict__ Axl,
                       f16* __restrict__ Ah0h, f16* __restrict__ Ah0l,
                       unsigned long long* __restrict__ keys, int* __restrict__ active,
                       float* __restrict__ out)
{
    if (blockIdx.x == 64) {
        for (int i = threadIdx.x; i < T * B; i += 256) out[i] = 0.0f;
        if (threadIdx.x < B) keys[threadIdx.x] = 0ull;
        if (threadIdx.x == 0) { active[0] = 1; active[1] = 0; }
        return;
    }
    const int b = blockIdx.x, mt = b >> 4;
    #pragma unroll
    for (int i = 0; i < 4; ++i) {
        const int k = threadIdx.x * 4 + i;
        const float hv = h_in[b * H + k];
        const float cv = c_in[b * H + k];
        h_t[k * B + b] = hv;
        c_t[k * B + b] = cv;
        const float xv = emb[H + k];            // SOS token row = 1
        const int chunk = k >> 5, lane = ((k >> 3) & 3) * 16 + (b & 15), j = k & 7;
        const size_t pos = ((size_t)(chunk * 4 + mt) * 64 + lane) * 8 + j;
        f16 hi = (f16)hv;
        Ah0h[pos] = hi; Ah0l[pos] = (f16)((hv - (float)hi) * SL);
        hi = (f16)xv;
        Axh[pos] = hi; Axl[pos] = (f16)((xv - (float)hi) * SL);
    }
}

// ---------------------------------------------------------------------------
// gates: C[64 b][16 n'] per block (n' = 4 k-cols x 4 gates), K=2048 split
// across 4 waves; fused bias + activations + c/h update + h-pack epilogue.
// ---------------------------------------------------------------------------
__global__ __launch_bounds__(256) void k_gates(
    const f16* __restrict__ Ghi, const f16* __restrict__ Glo,
    const f16* __restrict__ Axh, const f16* __restrict__ Axl,
    const f16* __restrict__ Ahh, const f16* __restrict__ Ahl,   // read (cur)
    f16* __restrict__ Anh, f16* __restrict__ Anl,               // write (next)
    const float* __restrict__ biasp, float* __restrict__ h_t, float* __restrict__ c_t,
    const int* __restrict__ active, int t)
{
    if (!active[t & 1]) return;
    const int tid = threadIdx.x;
    const int s = tid >> 6, lane = tid & 63;
    const int quad = lane >> 4, vl = lane & 15;
    const int nt = blockIdx.x;

    f32x4 acc0[4], acc1[4];
    #pragma unroll
    for (int mt = 0; mt < 4; ++mt) {
        acc0[mt] = (f32x4){0.f, 0.f, 0.f, 0.f};
        acc1[mt] = (f32x4){0.f, 0.f, 0.f, 0.f};
    }

    for (int c = s * 16; c < s * 16 + 16; ++c) {
        const f16* ah = (c < 32) ? Axh : Ahh;
        const f16* al = (c < 32) ? Axl : Ahl;
        const int cc = c & 31;
        const size_t wpos = ((size_t)(nt * 64 + c) * 64 + lane) * 8;
        const half8 whi = *(const half8*)&Ghi[wpos];
        const half8 wlo = *(const half8*)&Glo[wpos];
        #pragma unroll
        for (int mt = 0; mt < 4; ++mt) {
            const size_t apos = ((size_t)(cc * 4 + mt) * 64 + lane) * 8;
            const half8 ahi = *(const half8*)&ah[apos];
            const half8 alo = *(const half8*)&al[apos];
            acc0[mt] = __builtin_amdgcn_mfma_f32_16x16x32_f16(ahi, whi, acc0[mt], 0, 0, 0);
            acc1[mt] = __builtin_amdgcn_mfma_f32_16x16x32_f16(ahi, wlo, acc1[mt], 0, 0, 0);
            acc1[mt] = __builtin_amdgcn_mfma_f32_16x16x32_f16(alo, whi, acc1[mt], 0, 0, 0);
        }
    }

    __shared__ float red[4][64][16];   // [k-split][b][n'loc]
    __shared__ float gsum[64][17];
    #pragma unroll
    for (int mt = 0; mt < 4; ++mt)
        #pragma unroll
        for (int r = 0; r < 4; ++r)
            red[s][mt * 16 + quad * 4 + r][vl] = acc0[mt][r] * INV_HI + acc1[mt][r] * INV_LO;
    __syncthreads();
    #pragma unroll
    for (int i = 0; i < 4; ++i) {
        const int p = i * 256 + tid;
        const int b = p >> 4, v2 = p & 15;
        gsum[b][v2] = red[0][b][v2] + red[1][b][v2] + red[2][b][v2] + red[3][b][v2]
                    + biasp[nt * 16 + v2];
    }
    __syncthreads();
    {
        const int kk = tid >> 6, b = tid & 63;
        const float ig = sigmoidf_(gsum[b][kk * 4 + 0]);
        const float fg = sigmoidf_(gsum[b][kk * 4 + 1]);
        const float cg = tanhf(gsum[b][kk * 4 + 2]);
        const float og = sigmoidf_(gsum[b][kk * 4 + 3]);
        const int k = nt * 4 + kk;
        const float cv = c_t[k * B + b];
        const float cn = fg * cv + ig * cg;
        const float hn = og * tanhf(cn);
        c_t[k * B + b] = cn;
        h_t[k * B + b] = hn;
        const int chunk = k >> 5, mt = b >> 4, lane2 = ((k >> 3) & 3) * 16 + (b & 15), j = k & 7;
        const size_t pos = ((size_t)(chunk * 4 + mt) * 64 + lane2) * 8 + j;
        const f16 hi = (f16)hn;
        Anh[pos] = hi;
        Anl[pos] = (f16)((hn - (float)hi) * SL);
    }
}

// ---------------------------------------------------------------------------
// logits: block = 64 v-cols (wave w -> 16), M=64, K=1024; fused +out_b +std
// + packed-key argmax (atomicMax into keys[b]).
// ---------------------------------------------------------------------------
__global__ __launch_bounds__(256) void k_logits(
    const f16* __restrict__ Ahh, const f16* __restrict__ Ahl,
    const f16* __restrict__ Whi, const f16* __restrict__ Wlo,
    const float* __restrict__ out_b, const float* __restrict__ std_,
    unsigned long long* __restrict__ keys, int* __restrict__ active, int t)
{
    const int cur = t & 1;
    if (blockIdx.x == 0 && threadIdx.x == 0) active[cur ^ 1] = 0;  // reset next-flag
    if (!active[cur]) return;
    const int tid = threadIdx.x;
    const int w = tid >> 6, lane = tid & 63;
    const int quad = lane >> 4, vl = lane & 15;
    const int v0 = blockIdx.x * 64;
    const int vt = blockIdx.x * 4 + w;

    __shared__ float std_s[64][68];
    __shared__ unsigned long long wk[4][64];
    #pragma unroll
    for (int i = 0; i < 4; ++i) {
        const int p = i * 256 + tid;            // 1024 float4 loads
        const int row = p >> 4, cc = (p & 15) * 4;
        const float4 sv = *(const float4*)&std_[((size_t)t * B + row) * V + v0 + cc];
        *(float4*)&std_s[row][cc] = sv;
    }

    f32x4 acc0[4], acc1[4];
    #pragma unroll
    for (int mt = 0; mt < 4; ++mt) {
        acc0[mt] = (f32x4){0.f, 0.f, 0.f, 0.f};
        acc1[mt] = (f32x4){0.f, 0.f, 0.f, 0.f};
    }
    for (int c = 0; c < 32; ++c) {
        const size_t wpos = ((size_t)(vt * 32 + c) * 64 + lane) * 8;
        const half8 whi = *(const half8*)&Whi[wpos];
        const half8 wlo = *(const half8*)&Wlo[wpos];
        #pragma unroll
        for (int mt = 0; mt < 4; ++mt) {
            const size_t apos = ((size_t)(c * 4 + mt) * 64 + lane) * 8;
            const half8 ahi = *(const half8*)&Ahh[apos];
            const half8 alo = *(const half8*)&Ahl[apos];
            acc0[mt] = __builtin_amdgcn_mfma_f32_16x16x32_f16(ahi, whi, acc0[mt], 0, 0, 0);
            acc1[mt] = __builtin_amdgcn_mfma_f32_16x16x32_f16(ahi, wlo, acc1[mt], 0, 0, 0);
            acc1[mt] = __builtin_amdgcn_mfma_f32_16x16x32_f16(alo, whi, acc1[mt], 0, 0, 0);
        }
    }
    __syncthreads();

    const float outb = out_b[vt * 16 + vl];
    const int v = vt * 16 + vl;
    #pragma unroll
    for (int mt = 0; mt < 4; ++mt) {
        #pragma unroll
        for (int r = 0; r < 4; ++r) {
            const int b = mt * 16 + quad * 4 + r;
            const float val = acc0[mt][r] * INV_HI + acc1[mt][r] * INV_LO
                            + outb + std_s[b][w * 16 + vl];
            const uint32_t fb = __float_as_uint(val);
            const uint32_t mk = (fb & 0x80000000u) ? ~fb : (fb | 0x80000000u);
            unsigned long long key = ((unsigned long long)mk << 32)
                                   | (unsigned)(0x7FFFFFFF - v);
            #pragma unroll
            for (int m = 1; m < 16; m <<= 1) {
                const unsigned long long o = __shfl_xor(key, m, 16);
                if (o > key) key = o;
            }
            if (vl == 0) wk[w][b] = key;
        }
    }
    __syncthreads();
    if (tid < 64) {
        unsigned long long k0 = wk[0][tid];
        const unsigned long long k1 = wk[1][tid], k2 = wk[2][tid], k3 = wk[3][tid];
        if (k1 > k0) k0 = k1;
        if (k2 > k0) k0 = k2;
        if (k3 > k0) k0 = k3;
        atomicMax(&keys[tid], k0);
    }
}

// ---------------------------------------------------------------------------
// finalize step: decode argmax -> token, out write, active update,
// gather emb[tok] and pack into Ax fragments. grid 64 blocks x 64 thr.
// ---------------------------------------------------------------------------
__global__ void k_final(const float* __restrict__ emb,
                        unsigned long long* __restrict__ keys, int* __restrict__ active,
                        float* __restrict__ out,
                        f16* __restrict__ Axh, f16* __restrict__ Axl, int t)
{
    const int cur = t & 1;
    if (!active[cur]) return;
    const int b = blockIdx.x;
    const unsigned long long kk = keys[b];
    const int tokn = 0x7FFFFFFF - (int)(unsigned)(kk & 0xFFFFFFFFull);
    if (threadIdx.x == 0) {
        out[t * B + b] = (float)tokn;
        keys[b] = 0ull;
        if (tokn > 0) atomicOr(&active[cur ^ 1], 1);
    }
    const float* er = emb + (size_t)tokn * H;
    const int mt = b >> 4;
    #pragma unroll
    for (int r = 0; r < 2; ++r) {
        const int k0 = threadIdx.x * 16 + r * 8;
        const float4 x0 = *(const float4*)&er[k0];
        const float4 x1 = *(const float4*)&er[k0 + 4];
        const float xs[8] = {x0.x, x0.y, x0.z, x0.w, x1.x, x1.y, x1.z, x1.w};
        half8 h8, l8;
        #pragma unroll
        for (int j = 0; j < 8; ++j) {
            const f16 hi = (f16)xs[j];
            h8[j] = hi;
            l8[j] = (f16)((xs[j] - (float)hi) * SL);
        }
        const int chunk = k0 >> 5, lane = ((k0 >> 3) & 3) * 16 + (b & 15);
        const size_t pos = ((size_t)(chunk * 4 + mt) * 64 + lane) * 8;
        *(half8*)&Axh[pos] = h8;
        *(half8*)&Axl[pos] = l8;
    }
}

__global__ void k_fin(const float* __restrict__ h_t, float* __restrict__ out)
{
    const int idx = blockIdx.x * 256 + threadIdx.x;
    const int b = idx >> 10, k = idx & 1023;
    out[T * B + idx] = h_t[k * B + b];
}

extern "C" void kernel_launch(void* const* d_in, const int* in_sizes, int n_in,
                              void* d_out, int out_size, void* d_ws, size_t ws_size,
                              hipStream_t stream)
{
    const float* std_  = (const float*)d_in[1];
    const float* h_in  = (const float*)d_in[2];
    const float* c_in  = (const float*)d_in[3];
    const float* emb   = (const float*)d_in[4];
    const float* w_ih  = (const float*)d_in[5];
    const float* w_hh  = (const float*)d_in[6];
    const float* b_ih  = (const float*)d_in[7];
    const float* b_hh  = (const float*)d_in[8];
    const float* out_w = (const float*)d_in[9];
    const float* out_b = (const float*)d_in[10];
    float* out = (float*)d_out;

    // ---- workspace carve-up (halves first, 16B-aligned chunks) ----
    f16* Whi = (f16*)d_ws;                    // H*V
    f16* Wlo = Whi + (size_t)H * V;
    f16* Ghi = Wlo + (size_t)H * V;           // 2048*4096
    f16* Glo = Ghi + (size_t)2048 * 4096;
    f16* Axh = Glo + (size_t)2048 * 4096;     // B*H each
    f16* Axl = Axh + B * H;
    f16* Ah0h = Axl + B * H;
    f16* Ah0l = Ah0h + B * H;
    f16* Ah1h = Ah0l + B * H;
    f16* Ah1l = Ah1h + B * H;
    float* biasp = (float*)(Ah1l + B * H);    // 4096
    float* h_t = biasp + 4096;                // B*H
    float* c_t = h_t + B * H;                 // B*H
    unsigned long long* keys = (unsigned long long*)(c_t + B * H);  // 64
    int* active = (int*)(keys + B);           // 2

    f16* AhH[2] = {Ah0h, Ah1h};
    f16* AhL[2] = {Ah0l, Ah1l};

    k_packw<<<VT * 8, 256, 0, stream>>>(out_w, Whi, Wlo);
    k_packg<<<GNT * 16, 256, 0, stream>>>(w_ih, w_hh, Ghi, Glo);
    k_packbias<<<16, 256, 0, stream>>>(b_ih, b_hh, biasp);
    k_init<<<65, 256, 0, stream>>>(h_in, c_in, emb, h_t, c_t, Axh, Axl,
                                   Ah0h, Ah0l, keys, active, out);
    for (int t = 0; t < T; ++t) {
        const int cur = t & 1, nxt = cur ^ 1;
        k_gates<<<GNT, 256, 0, stream>>>(Ghi, Glo, Axh, Axl, AhH[cur], AhL[cur],
                                         AhH[nxt], AhL[nxt], biasp, h_t, c_t, active, t);
        k_logits<<<V / 64, 256, 0, stream>>>(AhH[nxt], AhL[nxt], Whi, Wlo,
                                             out_b, std_, keys, active, t);
        k_final<<<64, 64, 0, stream>>>(emb, keys, active, out, Axh, Axl, t);
    }
    k_fin<<<256, 256, 0, stream>>>(h_t, out);
}